// Round 5
// baseline (550.802 us; speedup 1.0000x reference)
//
#include <hip/hip_runtime.h>
#include <math.h>
#include <float.h>

#define BATCH 4
#define CH    256
#define NT    4096
#define NCTX  8192
#define KI    8

// coarse-selection geometry
#define CSEL    10                 // per-split top-C after merges (>=8 => safe)
#define DNSPLIT 4                  // ctx splits
#define CTX_PER (NCTX / DNSPLIT)   // 2048
#define NTILE   (CTX_PER / 32)     // 64 tiles of 32 ctx
#define NCAND   (DNSPLIT * CSEL)   // 40 candidates per target

typedef __attribute__((ext_vector_type(8)))  __bf16 bf16x8;
typedef __attribute__((ext_vector_type(16))) float  f32x16;

__device__ __forceinline__ unsigned short bf16_rne(float v) {
  unsigned u = __float_as_uint(v);
  return (unsigned short)((u + 0x7fffu + ((u >> 16) & 1u)) >> 16);
}

// ---------------- transpose: channel-major [CH][NT] -> node-major [NT][CH], fp32 + bf16 hi/lo ----------------
__global__ __launch_bounds__(256) void k_transpose2(const float* __restrict__ src,
                                                    float* __restrict__ dstF,
                                                    unsigned short* __restrict__ dstH,
                                                    unsigned short* __restrict__ dstL,
                                                    long dstBatch) {
  __shared__ float tile[32][33];
  const float* s = src + (long)blockIdx.z * CH * NT;
  float* dF = dstF + (long)blockIdx.z * dstBatch;
  unsigned short* dH = dstH + (long)blockIdx.z * dstBatch;
  unsigned short* dL = dstL + (long)blockIdx.z * dstBatch;
  const int m0 = blockIdx.x * 32, c0 = blockIdx.y * 32;
  const int tx = threadIdx.x, ty = threadIdx.y;
#pragma unroll
  for (int i = ty; i < 32; i += 8)
    tile[i][tx] = s[(long)(c0 + i) * NT + (m0 + tx)];
  __syncthreads();
#pragma unroll
  for (int i = ty; i < 32; i += 8) {
    float v = tile[tx][i];
    long o = (long)(m0 + i) * CH + (c0 + tx);
    dF[o] = v;
    unsigned short h = bf16_rne(v);
    dH[o] = h;
    float hf = __uint_as_float((unsigned)h << 16);
    dL[o] = bf16_rne(v - hf);
  }
}

// ---------------- W transpose: fp32 [CH(k)][CH(n)] -> bf16 hi/lo WT[n][k] ----------------
__global__ __launch_bounds__(256) void k_wtrans(const float* __restrict__ W,
                                                unsigned short* __restrict__ WTh,
                                                unsigned short* __restrict__ WTl) {
  __shared__ float tile[32][33];
  const int n0 = blockIdx.x * 32, k0 = blockIdx.y * 32;
  const int tx = threadIdx.x, ty = threadIdx.y;
#pragma unroll
  for (int i = ty; i < 32; i += 8)
    tile[i][tx] = W[(k0 + i) * CH + (n0 + tx)];   // W[k][n]
  __syncthreads();
#pragma unroll
  for (int i = ty; i < 32; i += 8) {
    float v = tile[tx][i];                        // = W[k0+tx][n0+i]
    int o = (n0 + i) * CH + (k0 + tx);            // WT[n][k]
    unsigned short h = bf16_rne(v);
    WTh[o] = h;
    float hf = __uint_as_float((unsigned)h << 16);
    WTl[o] = bf16_rne(v - hf);
  }
}

// ---------------- context norms: stores -0.5*|c|^2 (coarse ranking only) ----------------
__global__ __launch_bounds__(256) void k_norms(const float* __restrict__ xc1,
                                               const float* __restrict__ xc2,
                                               float* __restrict__ nrm) {
  const int j = blockIdx.x * 256 + threadIdx.x;
  const int b = blockIdx.y;
  const float* src = (j < NT) ? (xc1 + (long)b * CH * NT + j)
                              : (xc2 + (long)b * CH * NT + (j - NT));
  float acc = 0.f;
#pragma unroll 8
  for (int c = 0; c < CH; ++c) {
    float v = src[(long)c * NT];
    acc = fmaf(v, v, acc);
  }
  nrm[(long)b * NCTX + j] = -0.5f * acc;
}

// ---------------- MFMA coarse scorer + per-lane top-CSEL, v3 ----------------
// 128-thread blocks (2 waves x 32 targets), grid 1024. Dual acc (even/odd k-step)
// + dual kd lists (even/odd reg) for ILP; nrm read from global (L1-resident).
// C/D layout: col = lane&31 (target), row = (reg&3) + 8*(reg>>2) + 4*(lane>>5) (ctx).
// acc init with -0.5*|c|^2 so score = -2*acc + 512 = d^2 - |t|^2 + 512 > 0.
// key = (float_bits(score) & ~0x7FF) | local_ctx_idx.
__global__ __launch_bounds__(128) void k_dist_mfma(const __bf16* __restrict__ XcB,
                                                   const __bf16* __restrict__ XtB,
                                                   const float* __restrict__ nrm,
                                                   int* __restrict__ cand) {
  __shared__ __bf16 lds[2][32 * CH];   // 2 x 16 KB ctx tiles, fragment-linear order
  const int b = blockIdx.y, split = blockIdx.z;
  const int t = threadIdx.x, w = t >> 6, lane = t & 63;
  const int l31 = lane & 31, lh = lane >> 5;
  const int tgt0 = blockIdx.x * 64 + w * 32;
  const int cbase = split * CTX_PER;
  const float* nrmp = nrm + (long)b * NCTX + cbase;   // -0.5*|c|^2

  // B fragments (targets), K=256 in 16 k-steps, register-resident
  const __bf16* tp = XtB + ((long)b * NT + tgt0 + l31) * CH + lh * 8;
  bf16x8 bfrag[16];
#pragma unroll
  for (int s = 0; s < 16; ++s) bfrag[s] = *(const bf16x8*)(tp + s * 16);

  unsigned kdA[CSEL], kdB[CSEL];
#pragma unroll
  for (int q = 0; q < CSEL; ++q) { kdA[q] = 0xFFFFFFFFu; kdB[q] = 0xFFFFFFFFu; }

  const __bf16* cp = XcB + ((long)b * NCTX + cbase + l31) * CH;

  // stage tile jt into lds[buf]: chunk c holds ctx=lane&31, k8=c*2+(lane>>5)
  // -> LDS linear at c*1024B + lane*16B; k-step ds_read is conflict-free.
  auto STAGE = [&](int buf, int jt) {
#pragma unroll
    for (int r = 0; r < 8; ++r) {
      int c = r * 2 + w;
      const __bf16* src = cp + (long)jt * 32 * CH + (c * 2 + lh) * 8;
      __bf16* dst = &lds[buf][c * 512];   // wave-uniform base; HW adds lane*16
      __builtin_amdgcn_global_load_lds((const __attribute__((address_space(1))) void*)src,
                                       (__attribute__((address_space(3))) void*)dst,
                                       16, 0, 0);
    }
  };

  STAGE(0, 0);
  __syncthreads();

  int cur = 0;
  for (int jt = 0; jt < NTILE; ++jt) {
    if (jt + 1 < NTILE) STAGE(cur ^ 1, jt + 1);

    const int ct0 = jt * 32;
    f32x16 accA, accB;
#pragma unroll
    for (int g = 0; g < 4; ++g) {      // accA[4g+j] = -0.5*nrm[ct0 + 8g + 4lh + j]
      float4 nv = *(const float4*)&nrmp[ct0 + 8 * g + 4 * lh];
      accA[4 * g + 0] = nv.x; accA[4 * g + 1] = nv.y;
      accA[4 * g + 2] = nv.z; accA[4 * g + 3] = nv.w;
      accB[4 * g + 0] = 0.f;  accB[4 * g + 1] = 0.f;
      accB[4 * g + 2] = 0.f;  accB[4 * g + 3] = 0.f;
    }
#pragma unroll
    for (int s = 0; s < 16; s += 2) {   // two independent MFMA chains
      bf16x8 a0 = *(const bf16x8*)(&lds[cur][s * 512 + lane * 8]);
      bf16x8 a1 = *(const bf16x8*)(&lds[cur][(s + 1) * 512 + lane * 8]);
      accA = __builtin_amdgcn_mfma_f32_32x32x16_bf16(a0, bfrag[s], accA, 0, 0, 0);
      accB = __builtin_amdgcn_mfma_f32_32x32x16_bf16(a1, bfrag[s + 1], accB, 0, 0, 0);
    }

#pragma unroll
    for (int reg = 0; reg < 16; ++reg) {
      const int row = (reg & 3) + 8 * (reg >> 2) + lh * 4;
      float sc = fmaf(accA[reg] + accB[reg], -2.0f, 512.0f);
      unsigned key = (__float_as_uint(sc) & 0xFFFFF800u) | (unsigned)ct0 | (unsigned)row;
      if (reg & 1) {
#pragma unroll
        for (int q = 0; q < CSEL; ++q) {
          unsigned lo = min(key, kdB[q]); key = max(key, kdB[q]); kdB[q] = lo;
        }
      } else {
#pragma unroll
        for (int q = 0; q < CSEL; ++q) {
          unsigned lo = min(key, kdA[q]); key = max(key, kdA[q]); kdA[q] = lo;
        }
      }
    }
    __syncthreads();   // drains vmcnt (stage writes) + lgkm; frees read buffer
    cur ^= 1;
  }

  // merge kdB into kdA (one-time; kdA stays sorted ascending)
#pragma unroll
  for (int q = 0; q < CSEL; ++q) {
    unsigned key = kdB[q];
#pragma unroll
    for (int p = 0; p < CSEL; ++p) {
      unsigned lo = min(key, kdA[p]); key = max(key, kdA[p]); kdA[p] = lo;
    }
  }
  // merge the two lane-half sorted lists: lowest-CSEL of union = min(A[q], B[CSEL-1-q])
  unsigned oth[CSEL];
#pragma unroll
  for (int q = 0; q < CSEL; ++q) oth[q] = (unsigned)__shfl_xor((int)kdA[q], 32, 64);
  if (lh == 0) {
    long ob = (((long)b * NT + tgt0 + l31) * DNSPLIT + split) * CSEL;
#pragma unroll
    for (int q = 0; q < CSEL; ++q) {
      unsigned m = min(kdA[q], oth[CSEL - 1 - q]);
      cand[ob + q] = cbase + (int)(m & 0x7FFu);
    }
  }
}

// ---------------- fp64 exact rescore of NCAND candidates -> knn[8] ----------------
__global__ __launch_bounds__(64) void k_rescore(const float* __restrict__ XtT,
                                                const float* __restrict__ XcT,
                                                const int* __restrict__ cand,
                                                int* __restrict__ knn) {
  const int n = blockIdx.x, b = blockIdx.y, lane = threadIdx.x;
  const int grp = lane >> 4, gl = lane & 15;
  __shared__ double sd[NCAND];
  __shared__ int    sj[NCAND];
  const float* xt = XtT + ((long)b * NT + n) * CH + gl * 16;
  double xa[16];
#pragma unroll
  for (int r = 0; r < 4; ++r) {
    float4 v = *(const float4*)(xt + r * 4);
    xa[4 * r + 0] = (double)v.x; xa[4 * r + 1] = (double)v.y;
    xa[4 * r + 2] = (double)v.z; xa[4 * r + 3] = (double)v.w;
  }
  const int* cd = cand + ((long)b * NT + n) * NCAND;
  for (int q = grp; q < NCAND; q += 4) {
    int j = cd[q];
    const float* xc = XcT + ((long)b * NCTX + j) * CH + gl * 16;
    double acc = 0.0;
#pragma unroll
    for (int r = 0; r < 4; ++r) {
      float4 v = *(const float4*)(xc + r * 4);
      double d0 = xa[4 * r + 0] - (double)v.x; acc = fma(d0, d0, acc);
      double d1 = xa[4 * r + 1] - (double)v.y; acc = fma(d1, d1, acc);
      double d2 = xa[4 * r + 2] - (double)v.z; acc = fma(d2, d2, acc);
      double d3 = xa[4 * r + 3] - (double)v.w; acc = fma(d3, d3, acc);
    }
#pragma unroll
    for (int off = 8; off > 0; off >>= 1) acc += __shfl_xor(acc, off, 64);
    if (gl == 0) { sd[q] = acc; sj[q] = j; }
  }
  __syncthreads();
  double dq = (lane < NCAND) ? sd[lane] : DBL_MAX;
  int    jq = (lane < NCAND) ? sj[lane] : 0x7fffffff;
  int rank = 0;
  for (int i = 0; i < NCAND; ++i) {
    double di = sd[i]; int ji = sj[i];
    rank += (di < dq || (di == dq && ji < jq)) ? 1 : 0;
  }
  if (lane < NCAND && rank < KI)
    knn[((long)b * NT + n) * KI + rank] = jq;
}

// ---------------- counts (segment_sum of ones) ----------------
__global__ __launch_bounds__(256) void k_counts(const int* __restrict__ knn,
                                                unsigned* __restrict__ counts) {
  const int idx = blockIdx.x * 256 + threadIdx.x;   // over BATCH*NT
  const int b = idx >> 12;                          // NT = 4096
  const int* kn = knn + (long)idx * KI;
#pragma unroll
  for (int q = 0; q < KI; ++q) atomicAdd(&counts[(long)b * NCTX + kn[q]], 1u);
}

// ---------------- bf16 MFMA GEMM + bias, 3-term hi/lo split ----------------
// out[M][CH] fp32 = (Ah+Al)[M][CH] @ (Wh+Wl)[CH][CH] + bias, dropping Al*Wl.
// a-operand = A m-rows (LDS-staged fragment-linear), b-operand = WT n-rows (global,
// L2-resident). C/D: row=(reg&3)+8*(reg>>2)+4*lh (m), col=lane&31 (n).
__global__ __launch_bounds__(256) void k_gemm_mfma(const unsigned short* __restrict__ Ah,
                                                   const unsigned short* __restrict__ Al,
                                                   const unsigned short* __restrict__ WTh,
                                                   const unsigned short* __restrict__ WTl,
                                                   const float* __restrict__ bias,
                                                   float* __restrict__ out, int M) {
  __shared__ __bf16 ldsH[32 * CH];  // 16 KB
  __shared__ __bf16 ldsL[32 * CH];  // 16 KB
  const int b = blockIdx.y;
  const int m0 = blockIdx.x * 32;
  const int t = threadIdx.x, w = t >> 6, lane = t & 63;
  const int l31 = lane & 31, lh = lane >> 5;
  const long abase = (long)b * M * CH;
  const unsigned short* pH = Ah + abase + (long)(m0 + l31) * CH;
  const unsigned short* pL = Al + abase + (long)(m0 + l31) * CH;
#pragma unroll
  for (int r = 0; r < 4; ++r) {
    int c = r * 4 + w;
    __builtin_amdgcn_global_load_lds(
        (const __attribute__((address_space(1))) void*)(pH + (c * 2 + lh) * 8),
        (__attribute__((address_space(3))) void*)&ldsH[c * 512], 16, 0, 0);
    __builtin_amdgcn_global_load_lds(
        (const __attribute__((address_space(1))) void*)(pL + (c * 2 + lh) * 8),
        (__attribute__((address_space(3))) void*)&ldsL[c * 512], 16, 0, 0);
  }
  __syncthreads();

  const int n0 = w * 64;            // wave covers cols [n0, n0+64)
  f32x16 acc0, acc1;
#pragma unroll
  for (int i = 0; i < 16; ++i) { acc0[i] = 0.f; acc1[i] = 0.f; }
#pragma unroll
  for (int s = 0; s < 16; ++s) {
    bf16x8 ah = *(const bf16x8*)&ldsH[s * 512 + lane * 8];
    bf16x8 al = *(const bf16x8*)&ldsL[s * 512 + lane * 8];
    const int koff = lh * 8 + s * 16;
    bf16x8 bh0 = *(const bf16x8*)&WTh[(n0 + l31) * CH + koff];
    bf16x8 bl0 = *(const bf16x8*)&WTl[(n0 + l31) * CH + koff];
    bf16x8 bh1 = *(const bf16x8*)&WTh[(n0 + 32 + l31) * CH + koff];
    bf16x8 bl1 = *(const bf16x8*)&WTl[(n0 + 32 + l31) * CH + koff];
    acc0 = __builtin_amdgcn_mfma_f32_32x32x16_bf16(ah, bh0, acc0, 0, 0, 0);
    acc1 = __builtin_amdgcn_mfma_f32_32x32x16_bf16(ah, bh1, acc1, 0, 0, 0);
    acc0 = __builtin_amdgcn_mfma_f32_32x32x16_bf16(ah, bl0, acc0, 0, 0, 0);
    acc1 = __builtin_amdgcn_mfma_f32_32x32x16_bf16(ah, bl1, acc1, 0, 0, 0);
    acc0 = __builtin_amdgcn_mfma_f32_32x32x16_bf16(al, bh0, acc0, 0, 0, 0);
    acc1 = __builtin_amdgcn_mfma_f32_32x32x16_bf16(al, bh1, acc1, 0, 0, 0);
  }
  float* ob = out + abase;
  float bi0 = bias[n0 + l31], bi1 = bias[n0 + 32 + l31];
#pragma unroll
  for (int reg = 0; reg < 16; ++reg) {
    int row = (reg & 3) + 8 * (reg >> 2) + 4 * lh;
    ob[(long)(m0 + row) * CH + n0 + l31]      = acc0[reg] + bi0;
    ob[(long)(m0 + row) * CH + n0 + 32 + l31] = acc1[reg] + bi1;
  }
}

// ---------------- gather-mean: X_edge = (Xn_t + sum_k Xn_c[knn]) / 9 -> bf16 hi/lo ----------------
__global__ __launch_bounds__(256) void k_gather(const float* __restrict__ Xn_t,
                                                const float* __restrict__ Xn_c,
                                                const int* __restrict__ knn,
                                                unsigned short* __restrict__ XeH,
                                                unsigned short* __restrict__ XeL) {
  const int n = blockIdx.x, b = blockIdx.y, c = threadIdx.x;
  const int* kn = knn + ((long)b * NT + n) * KI;
  int j[KI];
#pragma unroll
  for (int q = 0; q < KI; ++q) j[q] = kn[q];
  float acc = Xn_t[((long)b * NT + n) * CH + c];
#pragma unroll
  for (int q = 0; q < KI; ++q) acc += Xn_c[((long)b * NCTX + j[q]) * CH + c];
  float xe = acc / 9.0f;
  long o = ((long)b * NT + n) * CH + c;
  unsigned short h = bf16_rne(xe);
  XeH[o] = h;
  float hf = __uint_as_float((unsigned)h << 16);
  XeL[o] = bf16_rne(xe - hf);
}

// ---------------- scatter-add contributions to context nodes ----------------
__global__ __launch_bounds__(256) void k_scatter(const float* __restrict__ Xet,
                                                 const int* __restrict__ knn,
                                                 float* __restrict__ contrib) {
  const int n = blockIdx.x, b = blockIdx.y, c = threadIdx.x;
  const float v = Xet[((long)b * NT + n) * CH + c];
  const int* kn = knn + ((long)b * NT + n) * KI;
#pragma unroll
  for (int q = 0; q < KI; ++q)
    atomicAdd(&contrib[((long)b * NCTX + kn[q]) * CH + c], v);
}

// ---------------- finalize target output: transpose [NT][CH] -> image [CH][NT] ----------------
__global__ __launch_bounds__(256) void k_fin_t(const float* __restrict__ Xet,
                                               float* __restrict__ out) {
  __shared__ float tile[32][33];
  const int b = blockIdx.z;
  const int n0 = blockIdx.x * 32, c0 = blockIdx.y * 32;
  const int tx = threadIdx.x, ty = threadIdx.y;
#pragma unroll
  for (int i = ty; i < 32; i += 8)
    tile[i][tx] = Xet[((long)b * NT + n0 + i) * CH + c0 + tx];
  __syncthreads();
#pragma unroll
  for (int i = ty; i < 32; i += 8)
    out[((long)b * CH + c0 + i) * NT + n0 + tx] = tile[tx][i];
}

// ---------------- finalize context outputs: divide by counts, transpose, split ----------------
__global__ __launch_bounds__(256) void k_fin_c(const float* __restrict__ contrib,
                                               const unsigned* __restrict__ counts,
                                               float* __restrict__ out1,
                                               float* __restrict__ out2) {
  __shared__ float tile[32][33];
  const int b = blockIdx.z;
  const int j0 = blockIdx.x * 32, c0 = blockIdx.y * 32;
  const int tx = threadIdx.x, ty = threadIdx.y;
#pragma unroll
  for (int i = ty; i < 32; i += 8) {
    float cnt = fmaxf((float)counts[(long)b * NCTX + j0 + i], 1.0f);
    tile[i][tx] = contrib[((long)b * NCTX + j0 + i) * CH + c0 + tx] / cnt;
  }
  __syncthreads();
  float* outp = (j0 < NT) ? (out1 + (long)b * CH * NT + j0)
                          : (out2 + (long)b * CH * NT + (j0 - NT));
#pragma unroll
  for (int i = ty; i < 32; i += 8)
    outp[(long)(c0 + i) * NT + tx] = tile[tx][i];
}

extern "C" void kernel_launch(void* const* d_in, const int* in_sizes, int n_in,
                              void* d_out, int out_size, void* d_ws, size_t ws_size,
                              hipStream_t stream) {
  const float* Xt  = (const float*)d_in[0];
  const float* Xc1 = (const float*)d_in[1];
  const float* Xc2 = (const float*)d_in[2];
  const float* W1  = (const float*)d_in[3];
  const float* b1  = (const float*)d_in[4];
  const float* W2  = (const float*)d_in[5];
  const float* b2  = (const float*)d_in[6];
  float* out = (float*)d_out;

  // ws layout (~69.4 MB):
  //   P: [B*NCTX*CH] f32   XcT -> (post-rescore) Xn_c -> (post-gather) contrib
  //   Q: [B*NT*CH]  f32    XtT -> (post-rescore) X_edge hi/lo bf16
  //   R: [B*NT*CH]  f32    Xn_t -> (post-gather) X_et
  //   nrm, counts, cand, knn, WT1h/l, WT2h/l
  float* P = (float*)d_ws;
  float* Q = P + (long)BATCH * NCTX * CH;
  float* R = Q + (long)BATCH * NT * CH;
  float* nrm = R + (long)BATCH * NT * CH;
  unsigned* counts = (unsigned*)(nrm + (long)BATCH * NCTX);
  int* cand = (int*)(counts + (long)BATCH * NCTX);
  int* knn = cand + (long)BATCH * NT * NCAND;
  unsigned short* WT1h = (unsigned short*)(knn + (long)BATCH * NT * KI);
  unsigned short* WT1l = WT1h + CH * CH;
  unsigned short* WT2h = WT1l + CH * CH;
  unsigned short* WT2l = WT2h + CH * CH;

  // d_out (50.33 MB) exactly fits the bf16 hi/lo staging buffers until gemm1 is done:
  //   [XcBh 16.78 | XtBh 8.39 | XcBl 16.78 | XtBl 8.39]  MB
  unsigned short* XcBh = (unsigned short*)d_out;
  unsigned short* XtBh = XcBh + (long)BATCH * NCTX * CH;
  unsigned short* XcBl = XtBh + (long)BATCH * NT * CH;
  unsigned short* XtBl = XcBl + (long)BATCH * NCTX * CH;

  float* Xn_c = P;                       // after rescore, P (XcT) is dead
  float* Xn_t = R;
  unsigned short* XeH = (unsigned short*)Q;   // after rescore, Q (XtT) is dead
  unsigned short* XeL = XeH + (long)BATCH * NT * CH;

  float* out_t  = out;
  float* out_c1 = out + (long)BATCH * CH * NT;
  float* out_c2 = out + 2L * BATCH * CH * NT;

  dim3 tb(32, 8);

  // W transposes to bf16 hi/lo (tiny, L2-resident afterwards)
  k_wtrans<<<dim3(8, 8), tb, 0, stream>>>(W1, WT1h, WT1l);
  k_wtrans<<<dim3(8, 8), tb, 0, stream>>>(W2, WT2h, WT2l);

  // node-major fp32 (rescore) + bf16 hi/lo (MFMA) copies
  k_transpose2<<<dim3(NT / 32, CH / 32, BATCH), tb, 0, stream>>>(Xt, Q, XtBh, XtBl, (long)NT * CH);
  k_transpose2<<<dim3(NT / 32, CH / 32, BATCH), tb, 0, stream>>>(Xc1, P, XcBh, XcBl, (long)NCTX * CH);
  k_transpose2<<<dim3(NT / 32, CH / 32, BATCH), tb, 0, stream>>>(Xc2, P + (long)NT * CH,
                                                                 XcBh + (long)NT * CH,
                                                                 XcBl + (long)NT * CH,
                                                                 (long)NCTX * CH);

  k_norms<<<dim3(NCTX / 256, BATCH), 256, 0, stream>>>(Xc1, Xc2, nrm);

  // MFMA coarse scoring + per-split top-10 -> 40 candidates per target
  k_dist_mfma<<<dim3(NT / 64, BATCH, DNSPLIT), 128, 0, stream>>>(
      (const __bf16*)XcBh, (const __bf16*)XtBh, nrm, cand);

  // exact fp64 rescore -> knn[8]
  k_rescore<<<dim3(NT, BATCH), 64, 0, stream>>>(Q, P, cand, knn);

  hipMemsetAsync(counts, 0, (size_t)BATCH * NCTX * 4, stream);
  k_counts<<<dim3(BATCH * NT / 256), 256, 0, stream>>>(knn, counts);

  // node2edge linear (bf16 MFMA, 3-term): Xn_t -> R, Xn_c -> P
  k_gemm_mfma<<<dim3(NT / 32, BATCH), 256, 0, stream>>>(XtBh, XtBl, WT1h, WT1l, b1, Xn_t, NT);
  k_gemm_mfma<<<dim3(NCTX / 32, BATCH), 256, 0, stream>>>(XcBh, XcBl, WT1h, WT1l, b1, Xn_c, NCTX);

  // edge mean-pool -> Q as bf16 hi/lo
  k_gather<<<dim3(NT, BATCH), 256, 0, stream>>>(Xn_t, Xn_c, knn, XeH, XeL);

  // edge2node linear: X_et -> R (Xn_t dead after gather)
  k_gemm_mfma<<<dim3(NT / 32, BATCH), 256, 0, stream>>>(XeH, XeL, WT2h, WT2l, b2, R, NT);

  // out_t (overwrites dead XcBh region of d_out)
  k_fin_t<<<dim3(NT / 32, CH / 32, BATCH), tb, 0, stream>>>(R, out_t);

  // context scatter-mean (P = Xn_c dead after gather -> contrib)
  hipMemsetAsync(P, 0, (size_t)BATCH * NCTX * CH * 4, stream);
  k_scatter<<<dim3(NT, BATCH), 256, 0, stream>>>(R, knn, P);
  k_fin_c<<<dim3(NCTX / 32, CH / 32, BATCH), tb, 0, stream>>>(P, counts, out_c1, out_c2);
}

// Round 6
// 441.007 us; speedup vs baseline: 1.2490x; 1.2490x over previous
//
#include <hip/hip_runtime.h>
#include <math.h>
#include <float.h>

#define BATCH 4
#define CH    256
#define NT    4096
#define NCTX  8192
#define KI    8

// coarse-selection geometry
#define CSEL    10                 // per-split top-C after lane-half merge (>=8 => safe)
#define DNSPLIT 8                  // ctx splits (grid fill)
#define CTX_PER (NCTX / DNSPLIT)   // 1024
#define NTILE   (CTX_PER / 32)     // 32 tiles of 32 ctx
#define NKEY    (DNSPLIT * CSEL)   // 80 packed keys per target
#define RESC    16                 // keys kept for exact fp64 rescore

typedef __attribute__((ext_vector_type(8)))  __bf16 bf16x8;
typedef __attribute__((ext_vector_type(16))) float  f32x16;

__device__ __forceinline__ unsigned short bf16_rne(float v) {
  unsigned u = __float_as_uint(v);
  return (unsigned short)((u + 0x7fffu + ((u >> 16) & 1u)) >> 16);
}

// ---------------- merged transpose: [CH][NT] -> [NT][CH] fp32 + bf16 hi/lo, + ctx norms ----------------
// z = which*4 + b; which: 0=Xt, 1=Xc1, 2=Xc2. For ctx, accumulates -0.5*|c|^2 into nrm (pre-zeroed).
__global__ __launch_bounds__(256) void k_transpose2(const float* __restrict__ Xt,
                                                    const float* __restrict__ Xc1,
                                                    const float* __restrict__ Xc2,
                                                    float* __restrict__ Q,
                                                    float* __restrict__ P,
                                                    unsigned short* __restrict__ XtBh,
                                                    unsigned short* __restrict__ XtBl,
                                                    unsigned short* __restrict__ XcBh,
                                                    unsigned short* __restrict__ XcBl,
                                                    float* __restrict__ nrm) {
  __shared__ float tile[32][33];
  __shared__ float ps[8][32];
  const int which = blockIdx.z >> 2, b = blockIdx.z & 3;
  const float* src;
  float* dF; unsigned short *dH, *dL; float* nrmp = nullptr;
  if (which == 0) {
    src = Xt + (long)b * CH * NT;
    dF = Q + (long)b * NT * CH;
    dH = XtBh + (long)b * NT * CH;  dL = XtBl + (long)b * NT * CH;
  } else if (which == 1) {
    src = Xc1 + (long)b * CH * NT;
    dF = P + (long)b * NCTX * CH;
    dH = XcBh + (long)b * NCTX * CH;  dL = XcBl + (long)b * NCTX * CH;
    nrmp = nrm + (long)b * NCTX;
  } else {
    src = Xc2 + (long)b * CH * NT;
    dF = P + ((long)b * NCTX + NT) * CH;
    dH = XcBh + ((long)b * NCTX + NT) * CH;  dL = XcBl + ((long)b * NCTX + NT) * CH;
    nrmp = nrm + (long)b * NCTX + NT;
  }
  const int m0 = blockIdx.x * 32, c0 = blockIdx.y * 32;
  const int tx = threadIdx.x, ty = threadIdx.y;
  float part = 0.f;
#pragma unroll
  for (int i = ty; i < 32; i += 8) {
    float v = src[(long)(c0 + i) * NT + (m0 + tx)];
    tile[i][tx] = v;
    part = fmaf(v, v, part);
  }
  if (which) ps[ty][tx] = part;
  __syncthreads();
#pragma unroll
  for (int i = ty; i < 32; i += 8) {
    float v = tile[tx][i];
    long o = (long)(m0 + i) * CH + (c0 + tx);
    dF[o] = v;
    unsigned short h = bf16_rne(v);
    dH[o] = h;
    float hf = __uint_as_float((unsigned)h << 16);
    dL[o] = bf16_rne(v - hf);
  }
  if (which && ty == 0) {
    float s = 0.f;
#pragma unroll
    for (int j = 0; j < 8; ++j) s += ps[j][tx];
    atomicAdd(&nrmp[m0 + tx], -0.5f * s);
  }
}

// ---------------- W transpose: fp32 [CH(k)][CH(n)] -> bf16 hi/lo WT[n][k]; z = which W ----------------
__global__ __launch_bounds__(256) void k_wtrans(const float* __restrict__ W1,
                                                const float* __restrict__ W2,
                                                unsigned short* __restrict__ WT1h,
                                                unsigned short* __restrict__ WT1l,
                                                unsigned short* __restrict__ WT2h,
                                                unsigned short* __restrict__ WT2l) {
  __shared__ float tile[32][33];
  const float* W = blockIdx.z ? W2 : W1;
  unsigned short* WTh = blockIdx.z ? WT2h : WT1h;
  unsigned short* WTl = blockIdx.z ? WT2l : WT1l;
  const int n0 = blockIdx.x * 32, k0 = blockIdx.y * 32;
  const int tx = threadIdx.x, ty = threadIdx.y;
#pragma unroll
  for (int i = ty; i < 32; i += 8)
    tile[i][tx] = W[(k0 + i) * CH + (n0 + tx)];   // W[k][n]
  __syncthreads();
#pragma unroll
  for (int i = ty; i < 32; i += 8) {
    float v = tile[tx][i];                        // = W[k0+tx][n0+i]
    int o = (n0 + i) * CH + (k0 + tx);            // WT[n][k]
    unsigned short h = bf16_rne(v);
    WTh[o] = h;
    float hf = __uint_as_float((unsigned)h << 16);
    WTl[o] = bf16_rne(v - hf);
  }
}

// ---------------- MFMA coarse scorer + per-lane top-CSEL (packed-key bubble), DNSPLIT=8 ----------------
// 256-thread blocks, 128 targets each, grid 1024 (4 blocks/CU). R4 body.
// C/D layout: col = lane&31 (target), row = (reg&3) + 8*(reg>>2) + 4*(lane>>5) (ctx).
// acc init with -0.5*|c|^2 so score = -2*acc + 512 = d^2 - |t|^2 + 512 > 0 (split-independent,
// so keys are comparable ACROSS splits). key = (float_bits(score) & ~0x7FF) | local_ctx_idx.
__global__ __launch_bounds__(256) void k_dist_mfma(const __bf16* __restrict__ XcB,
                                                   const __bf16* __restrict__ XtB,
                                                   const float* __restrict__ nrm,
                                                   unsigned* __restrict__ cand) {
  __shared__ __bf16 lds[2][32 * CH];   // 2 x 16 KB ctx tiles, fragment-linear order
  __shared__ float nrm_s[CTX_PER];     // 4 KB, holds -0.5*|c|^2
  const int b = blockIdx.y, split = blockIdx.z;
  const int t = threadIdx.x, w = t >> 6, lane = t & 63;
  const int l31 = lane & 31, lh = lane >> 5;
  const int tgt0 = blockIdx.x * 128 + w * 32;
  const int cbase = split * CTX_PER;

  for (int i = t; i < CTX_PER; i += 256)
    nrm_s[i] = nrm[(long)b * NCTX + cbase + i];

  // B fragments (targets), K=256 in 16 k-steps, register-resident
  const __bf16* tp = XtB + ((long)b * NT + tgt0 + l31) * CH + lh * 8;
  bf16x8 bfrag[16];
#pragma unroll
  for (int s = 0; s < 16; ++s) bfrag[s] = *(const bf16x8*)(tp + s * 16);

  unsigned kd[CSEL];
#pragma unroll
  for (int q = 0; q < CSEL; ++q) kd[q] = 0xFFFFFFFFu;

  const __bf16* cp = XcB + ((long)b * NCTX + cbase + l31) * CH;

  // stage tile jt into lds[buf]: chunk c=(r*4+w) holds ctx=lane&31, k8=c*2+(lane>>5)
  // -> LDS linear at c*1024B + lane*16B; k-step ds_read is conflict-free.
  auto STAGE = [&](int buf, int jt) {
#pragma unroll
    for (int r = 0; r < 4; ++r) {
      int c = r * 4 + w;
      const __bf16* src = cp + (long)jt * 32 * CH + (c * 2 + lh) * 8;
      __bf16* dst = &lds[buf][c * 512];   // wave-uniform base; HW adds lane*16
      __builtin_amdgcn_global_load_lds((const __attribute__((address_space(1))) void*)src,
                                       (__attribute__((address_space(3))) void*)dst,
                                       16, 0, 0);
    }
  };

  STAGE(0, 0);
  __syncthreads();

  int cur = 0;
  for (int jt = 0; jt < NTILE; ++jt) {
    if (jt + 1 < NTILE) STAGE(cur ^ 1, jt + 1);

    const int ct0 = jt * 32;
    f32x16 acc;
#pragma unroll
    for (int g = 0; g < 4; ++g) {      // acc[4g+j] = -0.5*|c|^2 [ct0 + 8g + 4lh + j]
      float4 nv = *(const float4*)&nrm_s[ct0 + 8 * g + 4 * lh];
      acc[4 * g + 0] = nv.x; acc[4 * g + 1] = nv.y;
      acc[4 * g + 2] = nv.z; acc[4 * g + 3] = nv.w;
    }
#pragma unroll
    for (int s = 0; s < 16; ++s) {
      bf16x8 a = *(const bf16x8*)(&lds[cur][s * 512 + lane * 8]);
      acc = __builtin_amdgcn_mfma_f32_32x32x16_bf16(a, bfrag[s], acc, 0, 0, 0);
    }

#pragma unroll
    for (int reg = 0; reg < 16; ++reg) {
      const int row = (reg & 3) + 8 * (reg >> 2) + lh * 4;
      float sc = fmaf(acc[reg], -2.0f, 512.0f);
      unsigned key = (__float_as_uint(sc) & 0xFFFFF800u) | (unsigned)ct0 | (unsigned)row;
#pragma unroll
      for (int q = 0; q < CSEL; ++q) {   // branchless sorted-ascending bubble insert
        unsigned lo = min(key, kd[q]);
        key = max(key, kd[q]);
        kd[q] = lo;
      }
    }
    __syncthreads();   // drains vmcnt (stage writes) + lgkm; frees read buffer
    cur ^= 1;
  }

  // merge the two lane-half sorted lists: lowest-CSEL of union = min(A[q], B[CSEL-1-q])
  unsigned oth[CSEL];
#pragma unroll
  for (int q = 0; q < CSEL; ++q) oth[q] = (unsigned)__shfl_xor((int)kd[q], 32, 64);
  if (lh == 0) {
    long ob = (((long)b * NT + tgt0 + l31) * DNSPLIT + split) * CSEL;
#pragma unroll
    for (int q = 0; q < CSEL; ++q)
      cand[ob + q] = min(kd[q], oth[CSEL - 1 - q]);   // raw key
  }
}

// ---------------- rescore: coarse top-16 of 80 keys, fp64 exact, rank-8 + counts ----------------
__global__ __launch_bounds__(64) void k_rescore(const float* __restrict__ XtT,
                                                const float* __restrict__ XcT,
                                                const unsigned* __restrict__ cand,
                                                int* __restrict__ knn,
                                                unsigned* __restrict__ counts) {
  const int n = blockIdx.x, b = blockIdx.y, lane = threadIdx.x;
  const int grp = lane >> 4, gl = lane & 15;
  __shared__ unsigned sk[NKEY];
  __shared__ int cidx[RESC];
  __shared__ double sd[RESC];
  __shared__ int sj[RESC];
  const unsigned* kp = cand + ((long)b * NT + n) * NKEY;
  unsigned k0 = kp[lane];
  unsigned k1 = (lane < NKEY - 64) ? kp[64 + lane] : 0xFFFFFFFFu;
  sk[lane] = k0;
  if (lane < NKEY - 64) sk[64 + lane] = k1;
  __syncthreads();
  int r0 = 0, r1 = 0;
  for (int i = 0; i < NKEY; ++i) {
    unsigned s = sk[i];
    r0 += (s < k0 || (s == k0 && i < lane)) ? 1 : 0;
    r1 += (s < k1 || (s == k1 && i < 64 + lane)) ? 1 : 0;
  }
  if (r0 < RESC) cidx[r0] = (lane / CSEL) * CTX_PER + (int)(k0 & 0x7FFu);
  if (lane < NKEY - 64 && r1 < RESC)
    cidx[r1] = ((64 + lane) / CSEL) * CTX_PER + (int)(k1 & 0x7FFu);
  __syncthreads();

  const float* xt = XtT + ((long)b * NT + n) * CH + gl * 16;
  double xa[16];
#pragma unroll
  for (int r = 0; r < 4; ++r) {
    float4 v = *(const float4*)(xt + r * 4);
    xa[4 * r + 0] = (double)v.x; xa[4 * r + 1] = (double)v.y;
    xa[4 * r + 2] = (double)v.z; xa[4 * r + 3] = (double)v.w;
  }
#pragma unroll
  for (int q0 = 0; q0 < RESC; q0 += 4) {
    int q = q0 + grp;
    int j = cidx[q];
    const float* xc = XcT + ((long)b * NCTX + j) * CH + gl * 16;
    double acc = 0.0;
#pragma unroll
    for (int r = 0; r < 4; ++r) {
      float4 v = *(const float4*)(xc + r * 4);
      double d0 = xa[4 * r + 0] - (double)v.x; acc = fma(d0, d0, acc);
      double d1 = xa[4 * r + 1] - (double)v.y; acc = fma(d1, d1, acc);
      double d2 = xa[4 * r + 2] - (double)v.z; acc = fma(d2, d2, acc);
      double d3 = xa[4 * r + 3] - (double)v.w; acc = fma(d3, d3, acc);
    }
#pragma unroll
    for (int off = 8; off > 0; off >>= 1) acc += __shfl_xor(acc, off, 64);
    if (gl == 0) { sd[q] = acc; sj[q] = j; }
  }
  __syncthreads();
  double dq = (lane < RESC) ? sd[lane] : DBL_MAX;
  int    jq = (lane < RESC) ? sj[lane] : 0x7fffffff;
  int rank = 0;
#pragma unroll
  for (int i = 0; i < RESC; ++i) {
    double di = sd[i]; int ji = sj[i];
    rank += (di < dq || (di == dq && ji < jq)) ? 1 : 0;
  }
  if (lane < RESC && rank < KI) {
    knn[((long)b * NT + n) * KI + rank] = jq;
    atomicAdd(&counts[(long)b * NCTX + jq], 1u);
  }
}

// ---------------- bf16 MFMA GEMM + bias, 3-term hi/lo split ----------------
__global__ __launch_bounds__(256) void k_gemm_mfma(const unsigned short* __restrict__ Ah,
                                                   const unsigned short* __restrict__ Al,
                                                   const unsigned short* __restrict__ WTh,
                                                   const unsigned short* __restrict__ WTl,
                                                   const float* __restrict__ bias,
                                                   float* __restrict__ out, int M) {
  __shared__ __bf16 ldsH[32 * CH];  // 16 KB
  __shared__ __bf16 ldsL[32 * CH];  // 16 KB
  const int b = blockIdx.y;
  const int m0 = blockIdx.x * 32;
  const int t = threadIdx.x, w = t >> 6, lane = t & 63;
  const int l31 = lane & 31, lh = lane >> 5;
  const long abase = (long)b * M * CH;
  const unsigned short* pH = Ah + abase + (long)(m0 + l31) * CH;
  const unsigned short* pL = Al + abase + (long)(m0 + l31) * CH;
#pragma unroll
  for (int r = 0; r < 4; ++r) {
    int c = r * 4 + w;
    __builtin_amdgcn_global_load_lds(
        (const __attribute__((address_space(1))) void*)(pH + (c * 2 + lh) * 8),
        (__attribute__((address_space(3))) void*)&ldsH[c * 512], 16, 0, 0);
    __builtin_amdgcn_global_load_lds(
        (const __attribute__((address_space(1))) void*)(pL + (c * 2 + lh) * 8),
        (__attribute__((address_space(3))) void*)&ldsL[c * 512], 16, 0, 0);
  }
  __syncthreads();

  const int n0 = w * 64;            // wave covers cols [n0, n0+64)
  f32x16 acc0, acc1;
#pragma unroll
  for (int i = 0; i < 16; ++i) { acc0[i] = 0.f; acc1[i] = 0.f; }
#pragma unroll
  for (int s = 0; s < 16; ++s) {
    bf16x8 ah = *(const bf16x8*)&ldsH[s * 512 + lane * 8];
    bf16x8 al = *(const bf16x8*)&ldsL[s * 512 + lane * 8];
    const int koff = lh * 8 + s * 16;
    bf16x8 bh0 = *(const bf16x8*)&WTh[(n0 + l31) * CH + koff];
    bf16x8 bl0 = *(const bf16x8*)&WTl[(n0 + l31) * CH + koff];
    bf16x8 bh1 = *(const bf16x8*)&WTh[(n0 + 32 + l31) * CH + koff];
    bf16x8 bl1 = *(const bf16x8*)&WTl[(n0 + 32 + l31) * CH + koff];
    acc0 = __builtin_amdgcn_mfma_f32_32x32x16_bf16(ah, bh0, acc0, 0, 0, 0);
    acc1 = __builtin_amdgcn_mfma_f32_32x32x16_bf16(ah, bh1, acc1, 0, 0, 0);
    acc0 = __builtin_amdgcn_mfma_f32_32x32x16_bf16(ah, bl0, acc0, 0, 0, 0);
    acc1 = __builtin_amdgcn_mfma_f32_32x32x16_bf16(ah, bl1, acc1, 0, 0, 0);
    acc0 = __builtin_amdgcn_mfma_f32_32x32x16_bf16(al, bh0, acc0, 0, 0, 0);
    acc1 = __builtin_amdgcn_mfma_f32_32x32x16_bf16(al, bh1, acc1, 0, 0, 0);
  }
  float* ob = out + abase;
  float bi0 = bias[n0 + l31], bi1 = bias[n0 + 32 + l31];
#pragma unroll
  for (int reg = 0; reg < 16; ++reg) {
    int row = (reg & 3) + 8 * (reg >> 2) + 4 * lh;
    ob[(long)(m0 + row) * CH + n0 + l31]      = acc0[reg] + bi0;
    ob[(long)(m0 + row) * CH + n0 + 32 + l31] = acc1[reg] + bi1;
  }
}

// ---------------- gather-mean: X_edge = (Xn_t + sum_k Xn_c[knn]) / 9 -> bf16 hi/lo ----------------
__global__ __launch_bounds__(256) void k_gather(const float* __restrict__ Xn_t,
                                                const float* __restrict__ Xn_c,
                                                const int* __restrict__ knn,
                                                unsigned short* __restrict__ XeH,
                                                unsigned short* __restrict__ XeL) {
  const int n = blockIdx.x, b = blockIdx.y, c = threadIdx.x;
  const int* kn = knn + ((long)b * NT + n) * KI;
  int j[KI];
#pragma unroll
  for (int q = 0; q < KI; ++q) j[q] = kn[q];
  float acc = Xn_t[((long)b * NT + n) * CH + c];
#pragma unroll
  for (int q = 0; q < KI; ++q) acc += Xn_c[((long)b * NCTX + j[q]) * CH + c];
  float xe = acc / 9.0f;
  long o = ((long)b * NT + n) * CH + c;
  unsigned short h = bf16_rne(xe);
  XeH[o] = h;
  float hf = __uint_as_float((unsigned)h << 16);
  XeL[o] = bf16_rne(xe - hf);
}

// ---------------- scatter-add contributions to context nodes ----------------
__global__ __launch_bounds__(256) void k_scatter(const float* __restrict__ Xet,
                                                 const int* __restrict__ knn,
                                                 float* __restrict__ contrib) {
  const int n = blockIdx.x, b = blockIdx.y, c = threadIdx.x;
  const float v = Xet[((long)b * NT + n) * CH + c];
  const int* kn = knn + ((long)b * NT + n) * KI;
#pragma unroll
  for (int q = 0; q < KI; ++q)
    atomicAdd(&contrib[((long)b * NCTX + kn[q]) * CH + c], v);
}

// ---------------- finalize target output: transpose [NT][CH] -> image [CH][NT] ----------------
__global__ __launch_bounds__(256) void k_fin_t(const float* __restrict__ Xet,
                                               float* __restrict__ out) {
  __shared__ float tile[32][33];
  const int b = blockIdx.z;
  const int n0 = blockIdx.x * 32, c0 = blockIdx.y * 32;
  const int tx = threadIdx.x, ty = threadIdx.y;
#pragma unroll
  for (int i = ty; i < 32; i += 8)
    tile[i][tx] = Xet[((long)b * NT + n0 + i) * CH + c0 + tx];
  __syncthreads();
#pragma unroll
  for (int i = ty; i < 32; i += 8)
    out[((long)b * CH + c0 + i) * NT + n0 + tx] = tile[tx][i];
}

// ---------------- finalize context outputs: divide by counts, transpose, split ----------------
__global__ __launch_bounds__(256) void k_fin_c(const float* __restrict__ contrib,
                                               const unsigned* __restrict__ counts,
                                               float* __restrict__ out1,
                                               float* __restrict__ out2) {
  __shared__ float tile[32][33];
  const int b = blockIdx.z;
  const int j0 = blockIdx.x * 32, c0 = blockIdx.y * 32;
  const int tx = threadIdx.x, ty = threadIdx.y;
#pragma unroll
  for (int i = ty; i < 32; i += 8) {
    float cnt = fmaxf((float)counts[(long)b * NCTX + j0 + i], 1.0f);
    tile[i][tx] = contrib[((long)b * NCTX + j0 + i) * CH + c0 + tx] / cnt;
  }
  __syncthreads();
  float* outp = (j0 < NT) ? (out1 + (long)b * CH * NT + j0)
                          : (out2 + (long)b * CH * NT + (j0 - NT));
#pragma unroll
  for (int i = ty; i < 32; i += 8)
    outp[(long)(c0 + i) * NT + tx] = tile[tx][i];
}

extern "C" void kernel_launch(void* const* d_in, const int* in_sizes, int n_in,
                              void* d_out, int out_size, void* d_ws, size_t ws_size,
                              hipStream_t stream) {
  const float* Xt  = (const float*)d_in[0];
  const float* Xc1 = (const float*)d_in[1];
  const float* Xc2 = (const float*)d_in[2];
  const float* W1  = (const float*)d_in[3];
  const float* b1  = (const float*)d_in[4];
  const float* W2  = (const float*)d_in[5];
  const float* b2  = (const float*)d_in[6];
  float* out = (float*)d_out;

  float* P = (float*)d_ws;
  float* Q = P + (long)BATCH * NCTX * CH;
  float* R = Q + (long)BATCH * NT * CH;
  float* nrm = R + (long)BATCH * NT * CH;
  unsigned* counts = (unsigned*)(nrm + (long)BATCH * NCTX);
  int* knn = (int*)(counts + (long)BATCH * NCTX);
  unsigned short* WT1h = (unsigned short*)(knn + (long)BATCH * NT * KI);
  unsigned short* WT1l = WT1h + CH * CH;
  unsigned short* WT2h = WT1l + CH * CH;
  unsigned short* WT2l = WT2h + CH * CH;

  unsigned* cand = (unsigned*)R;   // 5.24 MB, dead before gemm1 writes Xn_t to R

  unsigned short* XcBh = (unsigned short*)d_out;
  unsigned short* XtBh = XcBh + (long)BATCH * NCTX * CH;
  unsigned short* XcBl = XtBh + (long)BATCH * NT * CH;
  unsigned short* XtBl = XcBl + (long)BATCH * NCTX * CH;

  float* Xn_c = P;
  float* Xn_t = R;
  unsigned short* XeH = (unsigned short*)Q;
  unsigned short* XeL = XeH + (long)BATCH * NT * CH;

  float* out_t  = out;
  float* out_c1 = out + (long)BATCH * CH * NT;
  float* out_c2 = out + 2L * BATCH * CH * NT;

  dim3 tb(32, 8);

  hipMemsetAsync(nrm, 0, (size_t)BATCH * NCTX * 8, stream);   // nrm + counts

  k_wtrans<<<dim3(8, 8, 2), tb, 0, stream>>>(W1, W2, WT1h, WT1l, WT2h, WT2l);

  k_transpose2<<<dim3(NT / 32, CH / 32, 12), tb, 0, stream>>>(
      Xt, Xc1, Xc2, Q, P, XtBh, XtBl, XcBh, XcBl, nrm);

  k_dist_mfma<<<dim3(NT / 128, BATCH, DNSPLIT), 256, 0, stream>>>(
      (const __bf16*)XcBh, (const __bf16*)XtBh, nrm, cand);

  k_rescore<<<dim3(NT, BATCH), 64, 0, stream>>>(Q, P, cand, knn, counts);

  k_gemm_mfma<<<dim3(NT / 32, BATCH), 256, 0, stream>>>(XtBh, XtBl, WT1h, WT1l, b1, Xn_t, NT);
  k_gemm_mfma<<<dim3(NCTX / 32, BATCH), 256, 0, stream>>>(XcBh, XcBl, WT1h, WT1l, b1, Xn_c, NCTX);

  k_gather<<<dim3(NT, BATCH), 256, 0, stream>>>(Xn_t, Xn_c, knn, XeH, XeL);

  k_gemm_mfma<<<dim3(NT / 32, BATCH), 256, 0, stream>>>(XeH, XeL, WT2h, WT2l, b2, R, NT);

  k_fin_t<<<dim3(NT / 32, CH / 32, BATCH), tb, 0, stream>>>(R, out_t);

  hipMemsetAsync(P, 0, (size_t)BATCH * NCTX * CH * 4, stream);
  k_scatter<<<dim3(NT, BATCH), 256, 0, stream>>>(R, knn, P);
  k_fin_c<<<dim3(NCTX / 32, CH / 32, BATCH), tb, 0, stream>>>(P, counts, out_c1, out_c2);
}

// Round 7
// 437.177 us; speedup vs baseline: 1.2599x; 1.0088x over previous
//
#include <hip/hip_runtime.h>
#include <math.h>
#include <float.h>

#define BATCH 4
#define CH    256
#define NT    4096
#define NCTX  8192
#define KI    8

// coarse-selection geometry
#define CSEL    10                 // per-split top-C after lane-half merge (>=8 => safe)
#define DNSPLIT 8                  // ctx splits (grid fill)
#define CTX_PER (NCTX / DNSPLIT)   // 1024
#define NTILE   (CTX_PER / 32)     // 32 tiles of 32 ctx
#define NKEY    (DNSPLIT * CSEL)   // 80 packed keys per target
#define RESC    12                 // keys kept for exact fp64 rescore (gap(8->12)~3.7 >> noise ~0.6)

typedef __attribute__((ext_vector_type(8)))  __bf16 bf16x8;
typedef __attribute__((ext_vector_type(16))) float  f32x16;

__device__ __forceinline__ unsigned short bf16_rne(float v) {
  unsigned u = __float_as_uint(v);
  return (unsigned short)((u + 0x7fffu + ((u >> 16) & 1u)) >> 16);
}

// ---------------- merged transpose: [CH][NT] -> [NT][CH] fp32 + bf16 hi/lo, + ctx norms ----------------
// z = which*4 + b; which: 0=Xt, 1=Xc1, 2=Xc2. For ctx, accumulates -0.5*|c|^2 into nrm (pre-zeroed).
// 64-channel tiles; stores are float2 / ushort2 (vectorized, coalesced 128B+/wave).
__global__ __launch_bounds__(256) void k_transpose2(const float* __restrict__ Xt,
                                                    const float* __restrict__ Xc1,
                                                    const float* __restrict__ Xc2,
                                                    float* __restrict__ Q,
                                                    float* __restrict__ P,
                                                    unsigned short* __restrict__ XtBh,
                                                    unsigned short* __restrict__ XtBl,
                                                    unsigned short* __restrict__ XcBh,
                                                    unsigned short* __restrict__ XcBl,
                                                    float* __restrict__ nrm) {
  __shared__ float tile[64][33];
  __shared__ float ps[8][32];
  const int which = blockIdx.z >> 2, b = blockIdx.z & 3;
  const float* src;
  float* dF; unsigned short *dH, *dL; float* nrmp = nullptr;
  if (which == 0) {
    src = Xt + (long)b * CH * NT;
    dF = Q + (long)b * NT * CH;
    dH = XtBh + (long)b * NT * CH;  dL = XtBl + (long)b * NT * CH;
  } else if (which == 1) {
    src = Xc1 + (long)b * CH * NT;
    dF = P + (long)b * NCTX * CH;
    dH = XcBh + (long)b * NCTX * CH;  dL = XcBl + (long)b * NCTX * CH;
    nrmp = nrm + (long)b * NCTX;
  } else {
    src = Xc2 + (long)b * CH * NT;
    dF = P + ((long)b * NCTX + NT) * CH;
    dH = XcBh + ((long)b * NCTX + NT) * CH;  dL = XcBl + ((long)b * NCTX + NT) * CH;
    nrmp = nrm + (long)b * NCTX + NT;
  }
  const int m0 = blockIdx.x * 32, c0 = blockIdx.y * 64;
  const int tx = threadIdx.x, ty = threadIdx.y;
  float part = 0.f;
#pragma unroll
  for (int i = ty; i < 64; i += 8) {
    float v = src[(long)(c0 + i) * NT + (m0 + tx)];
    tile[i][tx] = v;
    part = fmaf(v, v, part);
  }
  if (which) ps[ty][tx] = part;
  __syncthreads();
#pragma unroll
  for (int i = ty; i < 32; i += 8) {
    float v0 = tile[2 * tx][i];       // 2-way LDS aliasing only (free)
    float v1 = tile[2 * tx + 1][i];
    long o = (long)(m0 + i) * CH + (c0 + 2 * tx);
    float2 f2; f2.x = v0; f2.y = v1;
    *(float2*)&dF[o] = f2;
    unsigned short h0 = bf16_rne(v0), h1 = bf16_rne(v1);
    ushort2 h2; h2.x = h0; h2.y = h1;
    *(ushort2*)&dH[o] = h2;
    float hf0 = __uint_as_float((unsigned)h0 << 16);
    float hf1 = __uint_as_float((unsigned)h1 << 16);
    ushort2 l2; l2.x = bf16_rne(v0 - hf0); l2.y = bf16_rne(v1 - hf1);
    *(ushort2*)&dL[o] = l2;
  }
  if (which && ty == 0) {
    float s = 0.f;
#pragma unroll
    for (int j = 0; j < 8; ++j) s += ps[j][tx];
    atomicAdd(&nrmp[m0 + tx], -0.5f * s);
  }
}

// ---------------- W transpose: fp32 [CH(k)][CH(n)] -> bf16 hi/lo WT[n][k]; z = which W ----------------
__global__ __launch_bounds__(256) void k_wtrans(const float* __restrict__ W1,
                                                const float* __restrict__ W2,
                                                unsigned short* __restrict__ WT1h,
                                                unsigned short* __restrict__ WT1l,
                                                unsigned short* __restrict__ WT2h,
                                                unsigned short* __restrict__ WT2l) {
  __shared__ float tile[32][33];
  const float* W = blockIdx.z ? W2 : W1;
  unsigned short* WTh = blockIdx.z ? WT2h : WT1h;
  unsigned short* WTl = blockIdx.z ? WT2l : WT1l;
  const int n0 = blockIdx.x * 32, k0 = blockIdx.y * 32;
  const int tx = threadIdx.x, ty = threadIdx.y;
#pragma unroll
  for (int i = ty; i < 32; i += 8)
    tile[i][tx] = W[(k0 + i) * CH + (n0 + tx)];   // W[k][n]
  __syncthreads();
#pragma unroll
  for (int i = ty; i < 32; i += 8) {
    float v = tile[tx][i];                        // = W[k0+tx][n0+i]
    int o = (n0 + i) * CH + (k0 + tx);            // WT[n][k]
    unsigned short h = bf16_rne(v);
    WTh[o] = h;
    float hf = __uint_as_float((unsigned)h << 16);
    WTl[o] = bf16_rne(v - hf);
  }
}

// ---------------- MFMA coarse scorer + per-lane top-CSEL (packed-key bubble), DNSPLIT=8 ----------------
// 256-thread blocks, 128 targets each, grid 1024. LDS = exactly 32 KB -> 5 blocks/CU.
// C/D layout: col = lane&31 (target), row = (reg&3) + 8*(reg>>2) + 4*(lane>>5) (ctx).
// acc init with -0.5*|c|^2 (global read, L1/L2-resident) so score = -2*acc + 512 > 0,
// split-independent => keys comparable across splits. key = (bits(score)&~0x7FF) | local_idx.
__global__ __launch_bounds__(256) void k_dist_mfma(const __bf16* __restrict__ XcB,
                                                   const __bf16* __restrict__ XtB,
                                                   const float* __restrict__ nrm,
                                                   unsigned* __restrict__ cand) {
  __shared__ __bf16 lds[2][32 * CH];   // 2 x 16 KB ctx tiles, fragment-linear order
  const int b = blockIdx.y, split = blockIdx.z;
  const int t = threadIdx.x, w = t >> 6, lane = t & 63;
  const int l31 = lane & 31, lh = lane >> 5;
  const int tgt0 = blockIdx.x * 128 + w * 32;
  const int cbase = split * CTX_PER;
  const float* nrmt = nrm + (long)b * NCTX + cbase;   // -0.5*|c|^2

  // B fragments (targets), K=256 in 16 k-steps, register-resident
  const __bf16* tp = XtB + ((long)b * NT + tgt0 + l31) * CH + lh * 8;
  bf16x8 bfrag[16];
#pragma unroll
  for (int s = 0; s < 16; ++s) bfrag[s] = *(const bf16x8*)(tp + s * 16);

  unsigned kd[CSEL];
#pragma unroll
  for (int q = 0; q < CSEL; ++q) kd[q] = 0xFFFFFFFFu;

  const __bf16* cp = XcB + ((long)b * NCTX + cbase + l31) * CH;

  // stage tile jt into lds[buf]: chunk c=(r*4+w) holds ctx=lane&31, k8=c*2+(lane>>5)
  // -> LDS linear at c*1024B + lane*16B; k-step ds_read is conflict-free.
  auto STAGE = [&](int buf, int jt) {
#pragma unroll
    for (int r = 0; r < 4; ++r) {
      int c = r * 4 + w;
      const __bf16* src = cp + (long)jt * 32 * CH + (c * 2 + lh) * 8;
      __bf16* dst = &lds[buf][c * 512];   // wave-uniform base; HW adds lane*16
      __builtin_amdgcn_global_load_lds((const __attribute__((address_space(1))) void*)src,
                                       (__attribute__((address_space(3))) void*)dst,
                                       16, 0, 0);
    }
  };

  STAGE(0, 0);
  __syncthreads();

  int cur = 0;
  for (int jt = 0; jt < NTILE; ++jt) {
    if (jt + 1 < NTILE) STAGE(cur ^ 1, jt + 1);

    const int ct0 = jt * 32;
    f32x16 acc;
#pragma unroll
    for (int g = 0; g < 4; ++g) {      // acc[4g+j] = -0.5*|c|^2 [ct0 + 8g + 4lh + j]
      float4 nv = *(const float4*)&nrmt[ct0 + 8 * g + 4 * lh];
      acc[4 * g + 0] = nv.x; acc[4 * g + 1] = nv.y;
      acc[4 * g + 2] = nv.z; acc[4 * g + 3] = nv.w;
    }
#pragma unroll
    for (int s = 0; s < 16; ++s) {
      bf16x8 a = *(const bf16x8*)(&lds[cur][s * 512 + lane * 8]);
      acc = __builtin_amdgcn_mfma_f32_32x32x16_bf16(a, bfrag[s], acc, 0, 0, 0);
    }

#pragma unroll
    for (int reg = 0; reg < 16; ++reg) {
      const int row = (reg & 3) + 8 * (reg >> 2) + lh * 4;
      float sc = fmaf(acc[reg], -2.0f, 512.0f);
      unsigned key = (__float_as_uint(sc) & 0xFFFFF800u) | (unsigned)ct0 | (unsigned)row;
#pragma unroll
      for (int q = 0; q < CSEL; ++q) {   // branchless sorted-ascending bubble insert
        unsigned lo = min(key, kd[q]);
        key = max(key, kd[q]);
        kd[q] = lo;
      }
    }
    __syncthreads();   // drains vmcnt (stage writes) + lgkm; frees read buffer
    cur ^= 1;
  }

  // merge the two lane-half sorted lists: lowest-CSEL of union = min(A[q], B[CSEL-1-q])
  unsigned oth[CSEL];
#pragma unroll
  for (int q = 0; q < CSEL; ++q) oth[q] = (unsigned)__shfl_xor((int)kd[q], 32, 64);
  if (lh == 0) {
    long ob = (((long)b * NT + tgt0 + l31) * DNSPLIT + split) * CSEL;
#pragma unroll
    for (int q = 0; q < CSEL; ++q)
      cand[ob + q] = min(kd[q], oth[CSEL - 1 - q]);   // raw key
  }
}

// ---------------- rescore: coarse top-RESC of 80 keys, fp64 exact, rank-8 + counts ----------------
__global__ __launch_bounds__(64) void k_rescore(const float* __restrict__ XtT,
                                                const float* __restrict__ XcT,
                                                const unsigned* __restrict__ cand,
                                                int* __restrict__ knn,
                                                unsigned* __restrict__ counts) {
  const int n = blockIdx.x, b = blockIdx.y, lane = threadIdx.x;
  const int grp = lane >> 4, gl = lane & 15;
  __shared__ unsigned sk[NKEY];
  __shared__ int cidx[RESC];
  __shared__ double sd[RESC];
  __shared__ int sj[RESC];
  const unsigned* kp = cand + ((long)b * NT + n) * NKEY;
  unsigned k0 = kp[lane];
  unsigned k1 = (lane < NKEY - 64) ? kp[64 + lane] : 0xFFFFFFFFu;
  sk[lane] = k0;
  if (lane < NKEY - 64) sk[64 + lane] = k1;
  __syncthreads();
  int r0 = 0, r1 = 0;
  for (int i = 0; i < NKEY; ++i) {
    unsigned s = sk[i];
    r0 += (s < k0 || (s == k0 && i < lane)) ? 1 : 0;
    r1 += (s < k1 || (s == k1 && i < 64 + lane)) ? 1 : 0;
  }
  if (r0 < RESC) cidx[r0] = (lane / CSEL) * CTX_PER + (int)(k0 & 0x7FFu);
  if (lane < NKEY - 64 && r1 < RESC)
    cidx[r1] = ((64 + lane) / CSEL) * CTX_PER + (int)(k1 & 0x7FFu);
  __syncthreads();

  const float* xt = XtT + ((long)b * NT + n) * CH + gl * 16;
  double xa[16];
#pragma unroll
  for (int r = 0; r < 4; ++r) {
    float4 v = *(const float4*)(xt + r * 4);
    xa[4 * r + 0] = (double)v.x; xa[4 * r + 1] = (double)v.y;
    xa[4 * r + 2] = (double)v.z; xa[4 * r + 3] = (double)v.w;
  }
#pragma unroll
  for (int q0 = 0; q0 < RESC; q0 += 4) {
    int q = q0 + grp;
    int j = cidx[q];
    const float* xc = XcT + ((long)b * NCTX + j) * CH + gl * 16;
    double acc = 0.0;
#pragma unroll
    for (int r = 0; r < 4; ++r) {
      float4 v = *(const float4*)(xc + r * 4);
      double d0 = xa[4 * r + 0] - (double)v.x; acc = fma(d0, d0, acc);
      double d1 = xa[4 * r + 1] - (double)v.y; acc = fma(d1, d1, acc);
      double d2 = xa[4 * r + 2] - (double)v.z; acc = fma(d2, d2, acc);
      double d3 = xa[4 * r + 3] - (double)v.w; acc = fma(d3, d3, acc);
    }
#pragma unroll
    for (int off = 8; off > 0; off >>= 1) acc += __shfl_xor(acc, off, 64);
    if (gl == 0) { sd[q] = acc; sj[q] = j; }
  }
  __syncthreads();
  double dq = (lane < RESC) ? sd[lane] : DBL_MAX;
  int    jq = (lane < RESC) ? sj[lane] : 0x7fffffff;
  int rank = 0;
#pragma unroll
  for (int i = 0; i < RESC; ++i) {
    double di = sd[i]; int ji = sj[i];
    rank += (di < dq || (di == dq && ji < jq)) ? 1 : 0;
  }
  if (lane < RESC && rank < KI) {
    knn[((long)b * NT + n) * KI + rank] = jq;
    atomicAdd(&counts[(long)b * NCTX + jq], 1u);
  }
}

// ---------------- bf16 MFMA GEMM + bias, 3-term hi/lo split ----------------
__global__ __launch_bounds__(256) void k_gemm_mfma(const unsigned short* __restrict__ Ah,
                                                   const unsigned short* __restrict__ Al,
                                                   const unsigned short* __restrict__ WTh,
                                                   const unsigned short* __restrict__ WTl,
                                                   const float* __restrict__ bias,
                                                   float* __restrict__ out, int M) {
  __shared__ __bf16 ldsH[32 * CH];  // 16 KB
  __shared__ __bf16 ldsL[32 * CH];  // 16 KB
  const int b = blockIdx.y;
  const int m0 = blockIdx.x * 32;
  const int t = threadIdx.x, w = t >> 6, lane = t & 63;
  const int l31 = lane & 31, lh = lane >> 5;
  const long abase = (long)b * M * CH;
  const unsigned short* pH = Ah + abase + (long)(m0 + l31) * CH;
  const unsigned short* pL = Al + abase + (long)(m0 + l31) * CH;
#pragma unroll
  for (int r = 0; r < 4; ++r) {
    int c = r * 4 + w;
    __builtin_amdgcn_global_load_lds(
        (const __attribute__((address_space(1))) void*)(pH + (c * 2 + lh) * 8),
        (__attribute__((address_space(3))) void*)&ldsH[c * 512], 16, 0, 0);
    __builtin_amdgcn_global_load_lds(
        (const __attribute__((address_space(1))) void*)(pL + (c * 2 + lh) * 8),
        (__attribute__((address_space(3))) void*)&ldsL[c * 512], 16, 0, 0);
  }
  __syncthreads();

  const int n0 = w * 64;            // wave covers cols [n0, n0+64)
  f32x16 acc0, acc1;
#pragma unroll
  for (int i = 0; i < 16; ++i) { acc0[i] = 0.f; acc1[i] = 0.f; }
#pragma unroll
  for (int s = 0; s < 16; ++s) {
    bf16x8 ah = *(const bf16x8*)&ldsH[s * 512 + lane * 8];
    bf16x8 al = *(const bf16x8*)&ldsL[s * 512 + lane * 8];
    const int koff = lh * 8 + s * 16;
    bf16x8 bh0 = *(const bf16x8*)&WTh[(n0 + l31) * CH + koff];
    bf16x8 bl0 = *(const bf16x8*)&WTl[(n0 + l31) * CH + koff];
    bf16x8 bh1 = *(const bf16x8*)&WTh[(n0 + 32 + l31) * CH + koff];
    bf16x8 bl1 = *(const bf16x8*)&WTl[(n0 + 32 + l31) * CH + koff];
    acc0 = __builtin_amdgcn_mfma_f32_32x32x16_bf16(ah, bh0, acc0, 0, 0, 0);
    acc1 = __builtin_amdgcn_mfma_f32_32x32x16_bf16(ah, bh1, acc1, 0, 0, 0);
    acc0 = __builtin_amdgcn_mfma_f32_32x32x16_bf16(ah, bl0, acc0, 0, 0, 0);
    acc1 = __builtin_amdgcn_mfma_f32_32x32x16_bf16(ah, bl1, acc1, 0, 0, 0);
    acc0 = __builtin_amdgcn_mfma_f32_32x32x16_bf16(al, bh0, acc0, 0, 0, 0);
    acc1 = __builtin_amdgcn_mfma_f32_32x32x16_bf16(al, bh1, acc1, 0, 0, 0);
  }
  float* ob = out + abase;
  float bi0 = bias[n0 + l31], bi1 = bias[n0 + 32 + l31];
#pragma unroll
  for (int reg = 0; reg < 16; ++reg) {
    int row = (reg & 3) + 8 * (reg >> 2) + 4 * lh;
    ob[(long)(m0 + row) * CH + n0 + l31]      = acc0[reg] + bi0;
    ob[(long)(m0 + row) * CH + n0 + 32 + l31] = acc1[reg] + bi1;
  }
}

// ---------------- gather-mean: X_edge = (Xn_t + sum_k Xn_c[knn]) / 9 -> bf16 hi/lo ----------------
__global__ __launch_bounds__(256) void k_gather(const float* __restrict__ Xn_t,
                                                const float* __restrict__ Xn_c,
                                                const int* __restrict__ knn,
                                                unsigned short* __restrict__ XeH,
                                                unsigned short* __restrict__ XeL) {
  const int n = blockIdx.x, b = blockIdx.y, c = threadIdx.x;
  const int* kn = knn + ((long)b * NT + n) * KI;
  int j[KI];
#pragma unroll
  for (int q = 0; q < KI; ++q) j[q] = kn[q];
  float acc = Xn_t[((long)b * NT + n) * CH + c];
#pragma unroll
  for (int q = 0; q < KI; ++q) acc += Xn_c[((long)b * NCTX + j[q]) * CH + c];
  float xe = acc / 9.0f;
  long o = ((long)b * NT + n) * CH + c;
  unsigned short h = bf16_rne(xe);
  XeH[o] = h;
  float hf = __uint_as_float((unsigned)h << 16);
  XeL[o] = bf16_rne(xe - hf);
}

// ---------------- scatter-add contributions to context nodes ----------------
__global__ __launch_bounds__(256) void k_scatter(const float* __restrict__ Xet,
                                                 const int* __restrict__ knn,
                                                 float* __restrict__ contrib) {
  const int n = blockIdx.x, b = blockIdx.y, c = threadIdx.x;
  const float v = Xet[((long)b * NT + n) * CH + c];
  const int* kn = knn + ((long)b * NT + n) * KI;
#pragma unroll
  for (int q = 0; q < KI; ++q)
    atomicAdd(&contrib[((long)b * NCTX + kn[q]) * CH + c], v);
}

// ---------------- finalize target output: transpose [NT][CH] -> image [CH][NT] ----------------
__global__ __launch_bounds__(256) void k_fin_t(const float* __restrict__ Xet,
                                               float* __restrict__ out) {
  __shared__ float tile[32][33];
  const int b = blockIdx.z;
  const int n0 = blockIdx.x * 32, c0 = blockIdx.y * 32;
  const int tx = threadIdx.x, ty = threadIdx.y;
#pragma unroll
  for (int i = ty; i < 32; i += 8)
    tile[i][tx] = Xet[((long)b * NT + n0 + i) * CH + c0 + tx];
  __syncthreads();
#pragma unroll
  for (int i = ty; i < 32; i += 8)
    out[((long)b * CH + c0 + i) * NT + n0 + tx] = tile[tx][i];
}

// ---------------- finalize context outputs: divide by counts, transpose, split ----------------
__global__ __launch_bounds__(256) void k_fin_c(const float* __restrict__ contrib,
                                               const unsigned* __restrict__ counts,
                                               float* __restrict__ out1,
                                               float* __restrict__ out2) {
  __shared__ float tile[32][33];
  const int b = blockIdx.z;
  const int j0 = blockIdx.x * 32, c0 = blockIdx.y * 32;
  const int tx = threadIdx.x, ty = threadIdx.y;
#pragma unroll
  for (int i = ty; i < 32; i += 8) {
    float cnt = fmaxf((float)counts[(long)b * NCTX + j0 + i], 1.0f);
    tile[i][tx] = contrib[((long)b * NCTX + j0 + i) * CH + c0 + tx] / cnt;
  }
  __syncthreads();
  float* outp = (j0 < NT) ? (out1 + (long)b * CH * NT + j0)
                          : (out2 + (long)b * CH * NT + (j0 - NT));
#pragma unroll
  for (int i = ty; i < 32; i += 8)
    outp[(long)(c0 + i) * NT + tx] = tile[tx][i];
}

extern "C" void kernel_launch(void* const* d_in, const int* in_sizes, int n_in,
                              void* d_out, int out_size, void* d_ws, size_t ws_size,
                              hipStream_t stream) {
  const float* Xt  = (const float*)d_in[0];
  const float* Xc1 = (const float*)d_in[1];
  const float* Xc2 = (const float*)d_in[2];
  const float* W1  = (const float*)d_in[3];
  const float* b1  = (const float*)d_in[4];
  const float* W2  = (const float*)d_in[5];
  const float* b2  = (const float*)d_in[6];
  float* out = (float*)d_out;

  float* P = (float*)d_ws;
  float* Q = P + (long)BATCH * NCTX * CH;
  float* R = Q + (long)BATCH * NT * CH;
  float* nrm = R + (long)BATCH * NT * CH;
  unsigned* counts = (unsigned*)(nrm + (long)BATCH * NCTX);
  int* knn = (int*)(counts + (long)BATCH * NCTX);
  unsigned short* WT1h = (unsigned short*)(knn + (long)BATCH * NT * KI);
  unsigned short* WT1l = WT1h + CH * CH;
  unsigned short* WT2h = WT1l + CH * CH;
  unsigned short* WT2l = WT2h + CH * CH;

  unsigned* cand = (unsigned*)R;   // 5.24 MB, dead before gemm1 writes Xn_t to R

  unsigned short* XcBh = (unsigned short*)d_out;
  unsigned short* XtBh = XcBh + (long)BATCH * NCTX * CH;
  unsigned short* XcBl = XtBh + (long)BATCH * NT * CH;
  unsigned short* XtBl = XcBl + (long)BATCH * NCTX * CH;

  float* Xn_c = P;
  float* Xn_t = R;
  unsigned short* XeH = (unsigned short*)Q;
  unsigned short* XeL = XeH + (long)BATCH * NT * CH;

  float* out_t  = out;
  float* out_c1 = out + (long)BATCH * CH * NT;
  float* out_c2 = out + 2L * BATCH * CH * NT;

  dim3 tb(32, 8);

  hipMemsetAsync(nrm, 0, (size_t)BATCH * NCTX * 8, stream);   // nrm + counts

  k_wtrans<<<dim3(8, 8, 2), tb, 0, stream>>>(W1, W2, WT1h, WT1l, WT2h, WT2l);

  k_transpose2<<<dim3(NT / 32, CH / 64, 12), tb, 0, stream>>>(
      Xt, Xc1, Xc2, Q, P, XtBh, XtBl, XcBh, XcBl, nrm);

  k_dist_mfma<<<dim3(NT / 128, BATCH, DNSPLIT), 256, 0, stream>>>(
      (const __bf16*)XcBh, (const __bf16*)XtBh, nrm, cand);

  k_rescore<<<dim3(NT, BATCH), 64, 0, stream>>>(Q, P, cand, knn, counts);

  k_gemm_mfma<<<dim3(NT / 32, BATCH), 256, 0, stream>>>(XtBh, XtBl, WT1h, WT1l, b1, Xn_t, NT);
  k_gemm_mfma<<<dim3(NCTX / 32, BATCH), 256, 0, stream>>>(XcBh, XcBl, WT1h, WT1l, b1, Xn_c, NCTX);

  k_gather<<<dim3(NT, BATCH), 256, 0, stream>>>(Xn_t, Xn_c, knn, XeH, XeL);

  k_gemm_mfma<<<dim3(NT / 32, BATCH), 256, 0, stream>>>(XeH, XeL, WT2h, WT2l, b2, R, NT);

  k_fin_t<<<dim3(NT / 32, CH / 32, BATCH), tb, 0, stream>>>(R, out_t);

  hipMemsetAsync(P, 0, (size_t)BATCH * NCTX * CH * 4, stream);
  k_scatter<<<dim3(NT, BATCH), 256, 0, stream>>>(R, knn, P);
  k_fin_c<<<dim3(NCTX / 32, CH / 32, BATCH), tb, 0, stream>>>(P, counts, out_c1, out_c2);
}